// Round 22
// baseline (66.174 us; speedup 1.0000x reference)
//
#include <hip/hip_runtime.h>
#include <hip/hip_bf16.h>

// Problem sizes (fixed by the reference)
#define S_LEN 256     // sequence length (t)
#define DM    512     // d_model (k / d)
#define DR    512     // d_rnn (s)

typedef float f4 __attribute__((ext_vector_type(4)));
typedef float f2 __attribute__((ext_vector_type(2)));

// ws layout (floats):
//   xP   : f4[128][256]      at 0        (131072)   xP[kq][t] = x[t][4kq..4kq+3]
//   part : [8][1024][256]    at 131072   (2097152)

// Packed transpose: xP[kq][t] holds 4 consecutive k for one t, so the GEMM's
// x access is ONE coalesced dwordx4 per 4-k batch (4x fewer L2 requests than
// the scalar-dword k-walk).
__global__ __launch_bounds__(256) void k_transpose_x(const float* __restrict__ x,
                                                     f4* __restrict__ xP) {
    __shared__ float tile[32][33];
    const int k0 = blockIdx.x * 32;          // over DM=512
    const int t0 = blockIdx.y * 32;          // over S=256
    const int lx = threadIdx.x & 31;
    const int ly = threadIdx.x >> 5;         // 0..7
#pragma unroll
    for (int i = 0; i < 32; i += 8)
        tile[ly + i][lx] = x[(t0 + ly + i) * DM + k0 + lx];
    __syncthreads();
    // write: thread (kq'=ly 0..7, lt=lx 0..31) -> f4 of 4 k for t = t0+lt
    f4 v;
    v.x = tile[lx][4 * ly + 0];
    v.y = tile[lx][4 * ly + 1];
    v.z = tile[lx][4 * ly + 2];
    v.w = tile[lx][4 * ly + 3];
    xP[(k0 / 4 + ly) * S_LEN + t0 + lx] = v;
}

// grid(1024) = 128 s-quads x 8 k-eighths; 4 blocks/CU = 16 waves/CU.
// REUSE is the change: 8 W-rows per block halves total x-traffic to 64 MB
// (R20/R21 both moved 128 MB and both took ~16 us despite 2x occupancy:
// bandwidth-bound on redundant xT reads, not latency-bound). Packed f4
// x-loads cut L2 requests 4x. 32 FMA per x-load.
__global__ __launch_bounds__(256) void k_gemm(const f4* __restrict__ xP,
                                              const float* __restrict__ W1,
                                              float* __restrict__ part) {
    const int bx = blockIdx.x;        // 0..1023
    const int sq = bx >> 3;           // s-quad 0..127 (s = 4sq..4sq+3)
    const int ke = bx & 7;            // k-eighth 0..7 (k = 64ke..64ke+63)
    const int t  = threadIdx.x;

    const f4* __restrict__ W0 = reinterpret_cast<const f4*>(W1 + (4 * sq + 0) * DM + ke * 64);
    const f4* __restrict__ Wa = reinterpret_cast<const f4*>(W1 + (4 * sq + 1) * DM + ke * 64);
    const f4* __restrict__ Wb = reinterpret_cast<const f4*>(W1 + (4 * sq + 2) * DM + ke * 64);
    const f4* __restrict__ Wc = reinterpret_cast<const f4*>(W1 + (4 * sq + 3) * DM + ke * 64);
    const f4* __restrict__ W4 = reinterpret_cast<const f4*>(W1 + (DR + 4 * sq + 0) * DM + ke * 64);
    const f4* __restrict__ W5 = reinterpret_cast<const f4*>(W1 + (DR + 4 * sq + 1) * DM + ke * 64);
    const f4* __restrict__ W6 = reinterpret_cast<const f4*>(W1 + (DR + 4 * sq + 2) * DM + ke * 64);
    const f4* __restrict__ W7 = reinterpret_cast<const f4*>(W1 + (DR + 4 * sq + 3) * DM + ke * 64);

    const f4* __restrict__ xb = xP + (ke * 16) * S_LEN + t;

    float a0 = 0.f, a1 = 0.f, a2 = 0.f, a3 = 0.f;
    float a4 = 0.f, a5 = 0.f, a6 = 0.f, a7 = 0.f;

#pragma unroll 4
    for (int kk = 0; kk < 16; ++kk) {
        const f4 xv = xb[kk * S_LEN];                // ONE coalesced 16B/lane load
        const f4 w0 = W0[kk];                        // wave-uniform -> s_load
        const f4 w1 = Wa[kk];
        const f4 w2 = Wb[kk];
        const f4 w3 = Wc[kk];
        const f4 w4 = W4[kk];
        const f4 w5 = W5[kk];
        const f4 w6 = W6[kk];
        const f4 w7 = W7[kk];
        a0 = fmaf(xv.x, w0.x, a0); a0 = fmaf(xv.y, w0.y, a0);
        a0 = fmaf(xv.z, w0.z, a0); a0 = fmaf(xv.w, w0.w, a0);
        a1 = fmaf(xv.x, w1.x, a1); a1 = fmaf(xv.y, w1.y, a1);
        a1 = fmaf(xv.z, w1.z, a1); a1 = fmaf(xv.w, w1.w, a1);
        a2 = fmaf(xv.x, w2.x, a2); a2 = fmaf(xv.y, w2.y, a2);
        a2 = fmaf(xv.z, w2.z, a2); a2 = fmaf(xv.w, w2.w, a2);
        a3 = fmaf(xv.x, w3.x, a3); a3 = fmaf(xv.y, w3.y, a3);
        a3 = fmaf(xv.z, w3.z, a3); a3 = fmaf(xv.w, w3.w, a3);
        a4 = fmaf(xv.x, w4.x, a4); a4 = fmaf(xv.y, w4.y, a4);
        a4 = fmaf(xv.z, w4.z, a4); a4 = fmaf(xv.w, w4.w, a4);
        a5 = fmaf(xv.x, w5.x, a5); a5 = fmaf(xv.y, w5.y, a5);
        a5 = fmaf(xv.z, w5.z, a5); a5 = fmaf(xv.w, w5.w, a5);
        a6 = fmaf(xv.x, w6.x, a6); a6 = fmaf(xv.y, w6.y, a6);
        a6 = fmaf(xv.z, w6.z, a6); a6 = fmaf(xv.w, w6.w, a6);
        a7 = fmaf(xv.x, w7.x, a7); a7 = fmaf(xv.y, w7.y, a7);
        a7 = fmaf(xv.z, w7.z, a7); a7 = fmaf(xv.w, w7.w, a7);
    }

    float* __restrict__ pb = part + ke * (1024 * 256);
    pb[(4 * sq + 0) * 256 + t] = a0;                 // coalesced
    pb[(4 * sq + 1) * 256 + t] = a1;
    pb[(4 * sq + 2) * 256 + t] = a2;
    pb[(4 * sq + 3) * 256 + t] = a3;
    pb[(DR + 4 * sq + 0) * 256 + t] = a4;
    pb[(DR + 4 * sq + 1) * 256 + t] = a5;
    pb[(DR + 4 * sq + 2) * 256 + t] = a6;
    pb[(DR + 4 * sq + 3) * 256 + t] = a7;
}

// grid(256) x 256: R21's k_rec verbatim (measured 44.4us y-stream + folded
// 8-partial reduction + activation epilogue in the prologue).
__global__ __launch_bounds__(256) void k_rec(const float* __restrict__ x,
                                             const float* __restrict__ state0,
                                             const float* __restrict__ part,
                                             const float* __restrict__ b1,
                                             const float* __restrict__ Lam,
                                             f4* __restrict__ out4) {
    const int bx   = blockIdx.x;
    const int sp   = (bx & 7) * 32 + (bx >> 3);   // bijective XCD s-banding
    const int tid  = threadIdx.x;
    const int half = tid >> 7;           // 0 or 1
    const int s    = sp * 2 + half;
    const int dq   = tid & 127;          // d/4

    __shared__ f2 ac_l[2][S_LEN];        // {a, c} per (half, t)

    // ---- folded act: reduce 8 k-partials + activations -> ac_l ----
    const int P = 1024 * 256;
#pragma unroll
    for (int sl = 0; sl < 2; ++sl) {
        const int srow = sp * 2 + sl;
        float pi = b1[srow];
        float pr = b1[DR + srow];
#pragma unroll
        for (int e = 0; e < 8; ++e) {
            pi += part[e * P + srow * 256 + tid];          // coalesced
            pr += part[e * P + (DR + srow) * 256 + tid];
        }
        const float inp = 1.f / (1.f + expf(-pi));         // sigmoid
        const float rec = 1.f / (1.f + expf(-pr));         // sigmoid
        const float sof = log1pf(expf(Lam[srow]));         // softplus
        const float a   = expf(-8.f * sof * rec);
        const float c   = sqrtf(fmaxf(1.f - a * a, 0.f)) * inp;
        f2 ac; ac.x = a; ac.y = c;
        ac_l[sl][tid] = ac;
    }

    const f4* __restrict__ st4 = reinterpret_cast<const f4*>(state0);
    f4 h = st4[s * 128 + dq];

    const f4* __restrict__ x4 = reinterpret_cast<const f4*>(x);
    f4 xv = x4[dq];                      // t = 0 prefetch

    __syncthreads();                     // ac_l ready

#pragma unroll 4
    for (int t = 0; t < S_LEN; ++t) {
        f4 xn;
        if (t + 1 < S_LEN) xn = x4[(t + 1) * 128 + dq];
        else xn = (f4)0.f;

        const f2 ac = ac_l[half][t];               // LDS broadcast (wave-uniform)
        const float at = ac.x, ct = ac.y;
        h.x = fmaf(at, h.x, ct * xv.x);
        h.y = fmaf(at, h.y, ct * xv.y);
        h.z = fmaf(at, h.z, ct * xv.z);
        h.w = fmaf(at, h.w, ct * xv.w);

        __builtin_nontemporal_store(h, &out4[(t * DR + s) * 128 + dq]);
        xv = xn;
    }
    // final state
    out4[(S_LEN * DR) * 128 + s * 128 + dq] = h;
}

extern "C" void kernel_launch(void* const* d_in, const int* in_sizes, int n_in,
                              void* d_out, int out_size, void* d_ws, size_t ws_size,
                              hipStream_t stream) {
    const float* x      = (const float*)d_in[0];
    const float* state0 = (const float*)d_in[1];
    const float* W1     = (const float*)d_in[2];
    const float* b1     = (const float*)d_in[3];
    const float* Lam    = (const float*)d_in[4];

    float* ws   = (float*)d_ws;
    f4*    xP   = (f4*)ws;                  // 131072 floats
    float* part = ws + 131072;              // 2097152 floats

    f4* out4 = (f4*)d_out;

    k_transpose_x<<<dim3(16, 8), 256, 0, stream>>>(x, xP);
    k_gemm<<<dim3(1024), 256, 0, stream>>>(xP, W1, part);
    k_rec<<<dim3(256), 256, 0, stream>>>(x, state0, part, b1, Lam, out4);
}